// Round 4
// baseline (2131.993 us; speedup 1.0000x reference)
//
#include <hip/hip_runtime.h>
#include <cstddef>

#define NF 64
#define EF 16
#define NH 128
#define EH 128
#define MA 256

static inline int ceil_div(int a, int b) { return (a + b - 1) / b; }

// ---------------- fp32 GEMM, 128x128 tile, 8x8 microtile, double-buffered LDS ----------------
// C[M,Nc] = act( reluA?(A[gatherA? gatherA[r]:r][K]) @ Bw[K,Nc] + addR[addIdx? addIdx[r]:r] + bias )
// 256 threads. M%128==0, Nc%128==0, K%16==0.
__global__ __launch_bounds__(256, 2) void gemm128_db(
    const float* __restrict__ A, const float* __restrict__ Bw,
    float* __restrict__ C,
    const float* __restrict__ addR, const int* __restrict__ addIdx,
    const float* __restrict__ bias, const int* __restrict__ gatherA,
    int M, int K, int Nc, int doRelu, int reluA)
{
    __shared__ float As[2][16][132];
    __shared__ float Bs[2][16][132];
    const int tid = threadIdx.x;
    const int tx = tid & 15;        // n: 8 cols each
    const int ty = tid >> 4;        // m: 8 rows each
    const int m0 = blockIdx.y << 7;
    const int n0 = blockIdx.x << 7;

    const int lr = tid >> 1;              // A row 0..127
    const int lc = (tid & 1) << 3;        // A col 0 or 8
    const int br = tid >> 4;              // B k-row 0..15
    const int bc = (tid & 15) << 3;       // B col 0..120

    float acc[8][8];
#pragma unroll
    for (int i = 0; i < 8; ++i)
#pragma unroll
        for (int j = 0; j < 8; ++j) acc[i][j] = 0.0f;

    int arow = gatherA ? gatherA[m0 + lr] : (m0 + lr);
    const float* aptr = A + (size_t)arow * K + lc;
    const float* bptr = Bw + (size_t)br * Nc + n0 + bc;

    // prefetch tile 0
    float4 a0 = *(const float4*)(aptr);
    float4 a1 = *(const float4*)(aptr + 4);
    float4 b0 = *(const float4*)(bptr);
    float4 b1 = *(const float4*)(bptr + 4);
    if (reluA) {
        a0.x = fmaxf(a0.x, 0.f); a0.y = fmaxf(a0.y, 0.f); a0.z = fmaxf(a0.z, 0.f); a0.w = fmaxf(a0.w, 0.f);
        a1.x = fmaxf(a1.x, 0.f); a1.y = fmaxf(a1.y, 0.f); a1.z = fmaxf(a1.z, 0.f); a1.w = fmaxf(a1.w, 0.f);
    }
    As[0][lc + 0][lr] = a0.x; As[0][lc + 1][lr] = a0.y; As[0][lc + 2][lr] = a0.z; As[0][lc + 3][lr] = a0.w;
    As[0][lc + 4][lr] = a1.x; As[0][lc + 5][lr] = a1.y; As[0][lc + 6][lr] = a1.z; As[0][lc + 7][lr] = a1.w;
    *(float4*)&Bs[0][br][bc] = b0;
    *(float4*)&Bs[0][br][bc + 4] = b1;
    __syncthreads();

#define GEMM_COMPUTE(BUF)                                                        \
    _Pragma("unroll")                                                            \
    for (int kk = 0; kk < 16; ++kk) {                                            \
        float4 av0 = *(const float4*)&As[BUF][kk][ty * 8];                       \
        float4 av1 = *(const float4*)&As[BUF][kk][ty * 8 + 4];                   \
        float4 bv0 = *(const float4*)&Bs[BUF][kk][tx * 8];                       \
        float4 bv1 = *(const float4*)&Bs[BUF][kk][tx * 8 + 4];                   \
        float a[8] = {av0.x, av0.y, av0.z, av0.w, av1.x, av1.y, av1.z, av1.w};   \
        float b[8] = {bv0.x, bv0.y, bv0.z, bv0.w, bv1.x, bv1.y, bv1.z, bv1.w};   \
        _Pragma("unroll")                                                        \
        for (int i = 0; i < 8; ++i)                                              \
            _Pragma("unroll")                                                    \
            for (int j = 0; j < 8; ++j)                                          \
                acc[i][j] = fmaf(a[i], b[j], acc[i][j]);                         \
    }

    const int nt = K >> 4;
    for (int t = 1; t < nt; ++t) {
        float4 na0 = *(const float4*)(aptr + t * 16);
        float4 na1 = *(const float4*)(aptr + t * 16 + 4);
        float4 nb0 = *(const float4*)(bptr + (size_t)t * 16 * Nc);
        float4 nb1 = *(const float4*)(bptr + (size_t)t * 16 * Nc + 4);
        if (reluA) {
            na0.x = fmaxf(na0.x, 0.f); na0.y = fmaxf(na0.y, 0.f); na0.z = fmaxf(na0.z, 0.f); na0.w = fmaxf(na0.w, 0.f);
            na1.x = fmaxf(na1.x, 0.f); na1.y = fmaxf(na1.y, 0.f); na1.z = fmaxf(na1.z, 0.f); na1.w = fmaxf(na1.w, 0.f);
        }
        const int cur = (t - 1) & 1, nxt = t & 1;
        if (cur == 0) { GEMM_COMPUTE(0) } else { GEMM_COMPUTE(1) }
        As[nxt][lc + 0][lr] = na0.x; As[nxt][lc + 1][lr] = na0.y; As[nxt][lc + 2][lr] = na0.z; As[nxt][lc + 3][lr] = na0.w;
        As[nxt][lc + 4][lr] = na1.x; As[nxt][lc + 5][lr] = na1.y; As[nxt][lc + 6][lr] = na1.z; As[nxt][lc + 7][lr] = na1.w;
        *(float4*)&Bs[nxt][br][bc] = nb0;
        *(float4*)&Bs[nxt][br][bc + 4] = nb1;
        __syncthreads();
    }
    if (((nt - 1) & 1) == 0) { GEMM_COMPUTE(0) } else { GEMM_COMPUTE(1) }
#undef GEMM_COMPUTE

    const int c = n0 + tx * 8;
    float4 bvl = make_float4(0.f, 0.f, 0.f, 0.f), bvh = bvl;
    if (bias) { bvl = *(const float4*)(bias + c); bvh = *(const float4*)(bias + c + 4); }
#pragma unroll
    for (int i = 0; i < 8; ++i) {
        int r = m0 + ty * 8 + i;
        float4 vl = make_float4(acc[i][0], acc[i][1], acc[i][2], acc[i][3]);
        float4 vh = make_float4(acc[i][4], acc[i][5], acc[i][6], acc[i][7]);
        if (addR) {
            int ar = addIdx ? addIdx[r] : r;
            float4 al = *(const float4*)(addR + (size_t)ar * Nc + c);
            float4 ah = *(const float4*)(addR + (size_t)ar * Nc + c + 4);
            vl.x += al.x; vl.y += al.y; vl.z += al.z; vl.w += al.w;
            vh.x += ah.x; vh.y += ah.y; vh.z += ah.z; vh.w += ah.w;
        }
        vl.x += bvl.x; vl.y += bvl.y; vl.z += bvl.z; vl.w += bvl.w;
        vh.x += bvh.x; vh.y += bvh.y; vh.z += bvh.z; vh.w += bvh.w;
        if (doRelu) {
            vl.x = fmaxf(vl.x, 0.f); vl.y = fmaxf(vl.y, 0.f); vl.z = fmaxf(vl.z, 0.f); vl.w = fmaxf(vl.w, 0.f);
            vh.x = fmaxf(vh.x, 0.f); vh.y = fmaxf(vh.y, 0.f); vh.z = fmaxf(vh.z, 0.f); vh.w = fmaxf(vh.w, 0.f);
        }
        *(float4*)(C + (size_t)r * Nc + c) = vl;
        *(float4*)(C + (size_t)r * Nc + c + 4) = vh;
    }
}

// ---------------- CSR build ----------------
__global__ __launch_bounds__(256) void hist_kernel(const int* __restrict__ dst, int* __restrict__ deg, int E) {
    int e = blockIdx.x * 256 + threadIdx.x;
    if (e < E) atomicAdd(&deg[dst[e]], 1);
}

// single-block scan over N elements (N % 1024 == 0), 1024 threads, 64 elems/thread
__global__ __launch_bounds__(1024) void scan_all_kernel(const int* __restrict__ deg, int* __restrict__ rp,
                                                        int* __restrict__ cursor, int N) {
    __shared__ int sums[1024];
    const int tid = threadIdx.x;
    const int per = N / 1024;
    const int base = tid * per;
    int tot = 0;
    for (int i = 0; i < per; ++i) tot += deg[base + i];
    sums[tid] = tot;
    __syncthreads();
    for (int off = 1; off < 1024; off <<= 1) {
        int t = (tid >= off) ? sums[tid - off] : 0;
        __syncthreads();
        sums[tid] += t;
        __syncthreads();
    }
    int prefix = sums[tid] - tot;  // exclusive
    for (int i = 0; i < per; ++i) {
        rp[base + i] = prefix;
        cursor[base + i] = prefix;
        prefix += deg[base + i];
    }
    if (tid == 1023) rp[N] = sums[1023];
}

// also emits srcS[p] = src[eid[p]] so agg reads sequentially
__global__ __launch_bounds__(256) void scatter_kernel(const int* __restrict__ dst, const int* __restrict__ src,
                                                      int* __restrict__ cursor,
                                                      int* __restrict__ eid, int* __restrict__ srcS, int E) {
    int e = blockIdx.x * 256 + threadIdx.x;
    if (e < E) {
        int p = atomicAdd(&cursor[dst[e]], 1);
        eid[p] = e;
        srcS[p] = src[e];
    }
}

// ---------------- edge aggregation via CSR (gather, sequential srcS/W2eS) ----------------
__global__ __launch_bounds__(256) void agg_kernel(const float* __restrict__ nodeT, const float* __restrict__ W2eS,
                                                  const int* __restrict__ rp, const int* __restrict__ srcS,
                                                  float* __restrict__ agg) {
    int n = blockIdx.x * 8 + threadIdx.y;
    int c = threadIdx.x << 2;
    int p0 = rp[n], p1 = rp[n + 1];
    float4 s = make_float4(0.f, 0.f, 0.f, 0.f);
    for (int p = p0; p < p1; ++p) {
        int sn = srcS[p];
        float4 t = *(const float4*)(nodeT + (size_t)sn * EH + c);
        float4 w = *(const float4*)(W2eS + (size_t)p * EH + c);
        s.x += fmaxf(t.x + w.x, 0.f);
        s.y += fmaxf(t.y + w.y, 0.f);
        s.z += fmaxf(t.z + w.z, 0.f);
        s.w += fmaxf(t.w + w.w, 0.f);
    }
    *(float4*)(agg + (size_t)n * EH + c) = s;
}

// ---------------- fused x3 GEMM + final dot + threshold ----------------
// per block: 128 rows. x3 = relu(x2[128,128] @ M3w[128,64] + b3); z = x3 @ M4w + b4; out = z>=0
__global__ __launch_bounds__(256) void x3final_kernel(const float* __restrict__ x2, const float* __restrict__ M3w,
                                                      const float* __restrict__ b3, const float* __restrict__ M4w,
                                                      const float* __restrict__ b4, int* __restrict__ out) {
    __shared__ float As[16][132];
    __shared__ float Bs[16][68];
    __shared__ float red[128][17];
    const int tid = threadIdx.x;
    const int tx = tid & 15;        // n: 4 cols each (64 total)
    const int ty = tid >> 4;        // m: 8 rows each
    const int m0 = blockIdx.x << 7;
    const int lr = tid >> 1, lc = (tid & 1) << 3;
    const int br = tid >> 4, bc = (tid & 15) << 2;

    float acc[8][4];
#pragma unroll
    for (int i = 0; i < 8; ++i)
#pragma unroll
        for (int j = 0; j < 4; ++j) acc[i][j] = 0.0f;

    const float* aptr = x2 + (size_t)(m0 + lr) * 128 + lc;
    for (int k0 = 0; k0 < 128; k0 += 16) {
        float4 a0 = *(const float4*)(aptr + k0);
        float4 a1 = *(const float4*)(aptr + k0 + 4);
        float4 bv = *(const float4*)(M3w + (size_t)(k0 + br) * 64 + bc);
        __syncthreads();
        As[lc + 0][lr] = a0.x; As[lc + 1][lr] = a0.y; As[lc + 2][lr] = a0.z; As[lc + 3][lr] = a0.w;
        As[lc + 4][lr] = a1.x; As[lc + 5][lr] = a1.y; As[lc + 6][lr] = a1.z; As[lc + 7][lr] = a1.w;
        *(float4*)&Bs[br][bc] = bv;
        __syncthreads();
#pragma unroll
        for (int kk = 0; kk < 16; ++kk) {
            float4 av0 = *(const float4*)&As[kk][ty * 8];
            float4 av1 = *(const float4*)&As[kk][ty * 8 + 4];
            float4 bv0 = *(const float4*)&Bs[kk][tx * 4];
            float a[8] = {av0.x, av0.y, av0.z, av0.w, av1.x, av1.y, av1.z, av1.w};
            float b[4] = {bv0.x, bv0.y, bv0.z, bv0.w};
#pragma unroll
            for (int i = 0; i < 8; ++i)
#pragma unroll
                for (int j = 0; j < 4; ++j)
                    acc[i][j] = fmaf(a[i], b[j], acc[i][j]);
        }
    }

    const int c = tx * 4;
    float4 b3v = *(const float4*)(b3 + c);
    float4 w4v = *(const float4*)(M4w + c);
#pragma unroll
    for (int i = 0; i < 8; ++i) {
        float p = fmaxf(acc[i][0] + b3v.x, 0.f) * w4v.x
                + fmaxf(acc[i][1] + b3v.y, 0.f) * w4v.y
                + fmaxf(acc[i][2] + b3v.z, 0.f) * w4v.z
                + fmaxf(acc[i][3] + b3v.w, 0.f) * w4v.w;
        red[ty * 8 + i][tx] = p;
    }
    __syncthreads();
    if (tid < 128) {
        float z = b4[0];
#pragma unroll
        for (int j = 0; j < 16; ++j) z += red[tid][j];
        out[m0 + tid] = z >= 0.f ? 1 : 0;
    }
}

extern "C" void kernel_launch(void* const* d_in, const int* in_sizes, int n_in,
                              void* d_out, int out_size, void* d_ws, size_t ws_size,
                              hipStream_t stream)
{
    const float* mol_a = (const float*)d_in[0];
    const float* nf    = (const float*)d_in[1];
    const float* ef    = (const float*)d_in[2];
    const int*   edges = (const int*)d_in[5];
    const int*   batch = (const int*)d_in[6];
    const float* W1  = (const float*)d_in[7];
    const float* W2  = (const float*)d_in[8];
    const float* W3  = (const float*)d_in[9];
    const float* U1  = (const float*)d_in[10];
    const float* U2  = (const float*)d_in[11];
    const float* M1w = (const float*)d_in[12];
    const float* M1b = (const float*)d_in[13];
    const float* M2w = (const float*)d_in[14];
    const float* M2b = (const float*)d_in[15];
    const float* M3w = (const float*)d_in[16];
    const float* M3b = (const float*)d_in[17];
    const float* M4w = (const float*)d_in[18];
    const float* M4b = (const float*)d_in[19];

    const int N = in_sizes[3] / NH;   // 65536
    const int E = in_sizes[4] / EH;   // 262144
    const int B = in_sizes[0] / MA;   // 2048
    const int* srcp = edges;
    const int* dstp = edges + E;

    char* ws = (char*)d_ws;
    size_t off = 0;
    auto alloc = [&](size_t bytes) -> char* {
        char* p = ws + off;
        off = (off + bytes + 255) & ~(size_t)255;
        return p;
    };
    int* deg     = (int*)alloc((size_t)N * 4);
    int* rp      = (int*)alloc(((size_t)N + 1) * 4);
    int* cursor  = (int*)alloc((size_t)N * 4);
    int* eid     = (int*)alloc((size_t)E * 4);
    int* srcS    = (int*)alloc((size_t)E * 4);
    float* nodePre = (float*)alloc((size_t)N * EH * 4);
    float* U1x     = (float*)alloc((size_t)N * NH * 4);
    float* node_h  = (float*)alloc((size_t)N * NH * 4);
    float* nodeT   = (float*)alloc((size_t)N * EH * 4);
    float* aggp    = (float*)alloc((size_t)N * EH * 4);
    float* molPart = (float*)alloc((size_t)B * 256 * 4);
    float* W2eS    = (float*)alloc((size_t)E * EH * 4);
    // MLP phase reuses dead buffers:
    float* x1 = (float*)W2eS;  // [N,256]
    float* x2 = nodeT;         // [N,128]

    // ---- CSR build (dst is loop-invariant) ----
    hipMemsetAsync(deg, 0, (size_t)N * 4, stream);
    hist_kernel<<<ceil_div(E, 256), 256, 0, stream>>>(dstp, deg, E);
    scan_all_kernel<<<1, 1024, 0, stream>>>(deg, rp, cursor, N);
    scatter_kernel<<<ceil_div(E, 256), 256, 0, stream>>>(dstp, srcp, cursor, eid, srcS, E);

    // ---- loop-invariant precompute ----
    gemm128_db<<<dim3(1, N / 128), 256, 0, stream>>>(nf, W1, nodePre, nullptr, nullptr, nullptr, nullptr, N, NF, EH, 0, 0);
    gemm128_db<<<dim3(1, E / 128), 256, 0, stream>>>(ef, W2, W2eS, nullptr, nullptr, nullptr, eid, E, EF, EH, 0, 0);
    gemm128_db<<<dim3(1, N / 128), 256, 0, stream>>>(nf, U1, U1x, nullptr, nullptr, nullptr, nullptr, N, NF, NH, 0, 0);

    // ---- step 1 fused: nodeT_1 = nodePre + relu(U1x) @ W3 ----
    gemm128_db<<<dim3(1, N / 128), 256, 0, stream>>>(U1x, W3, nodeT, nodePre, nullptr, nullptr, nullptr, N, NH, EH, 0, 1);

    // ---- steps 2..7 ----
    for (int s = 0; s < 6; ++s) {
        agg_kernel<<<N / 8, dim3(32, 8), 0, stream>>>(nodeT, W2eS, rp, srcS, aggp);
        gemm128_db<<<dim3(1, N / 128), 256, 0, stream>>>(aggp, U2, node_h, U1x, nullptr, nullptr, nullptr, N, EH, NH, 1, 0);
        gemm128_db<<<dim3(1, N / 128), 256, 0, stream>>>(node_h, W3, nodeT, nodePre, nullptr, nullptr, nullptr, N, NH, EH, 0, 0);
    }
    // ---- step 8: final node update ----
    agg_kernel<<<N / 8, dim3(32, 8), 0, stream>>>(nodeT, W2eS, rp, srcS, aggp);
    gemm128_db<<<dim3(1, N / 128), 256, 0, stream>>>(aggp, U2, node_h, U1x, nullptr, nullptr, nullptr, N, EH, NH, 1, 0);

    // ---- pick-atom MLP ----
    gemm128_db<<<dim3(2, B / 128), 256, 0, stream>>>(mol_a, M1w + 128 * 256, molPart, nullptr, nullptr, M1b, nullptr, B, MA, 256, 0, 0);
    gemm128_db<<<dim3(2, N / 128), 256, 0, stream>>>(node_h, M1w, x1, molPart, batch, nullptr, nullptr, N, NH, 256, 1, 0);
    gemm128_db<<<dim3(1, N / 128), 256, 0, stream>>>(x1, M2w, x2, nullptr, nullptr, M2b, nullptr, N, 256, 128, 1, 0);
    x3final_kernel<<<N / 128, 256, 0, stream>>>(x2, M3w, M3b, M4w, M4b, (int*)d_out);
}

// Round 5
// 1447.815 us; speedup vs baseline: 1.4726x; 1.4726x over previous
//
#include <hip/hip_runtime.h>
#include <cstddef>

#define NF 64
#define EF 16
#define NH 128
#define EH 128
#define MA 256

static inline int ceil_div(int a, int b) { return (a + b - 1) / b; }

// ---------------- fp32 GEMM, 128x128 tile, 8x8 microtile, single-buffered ----------------
// C = act( reluA?(A[gatherA? gatherA[r]:r][K]) @ Bw[K,Nc] + addR[addIdx? addIdx[r]:r] + bias )
__global__ __launch_bounds__(256) void gemm128_kernel(
    const float* __restrict__ A, const float* __restrict__ Bw,
    float* __restrict__ C,
    const float* __restrict__ addR, const int* __restrict__ addIdx,
    const float* __restrict__ bias, const int* __restrict__ gatherA,
    int M, int K, int Nc, int doRelu, int reluA)
{
    __shared__ float As[16][132];
    __shared__ float Bs[16][132];
    const int tid = threadIdx.x;
    const int tx = tid & 15;
    const int ty = tid >> 4;
    const int m0 = blockIdx.y << 7;
    const int n0 = blockIdx.x << 7;

    const int lr = tid >> 1;
    const int lc = (tid & 1) << 3;
    const int br = tid >> 4;
    const int bc = (tid & 15) << 3;

    float acc[8][8];
#pragma unroll
    for (int i = 0; i < 8; ++i)
#pragma unroll
        for (int j = 0; j < 8; ++j) acc[i][j] = 0.0f;

    int arow = gatherA ? gatherA[m0 + lr] : (m0 + lr);
    const float* aptr = A + (size_t)arow * K + lc;

    for (int k0 = 0; k0 < K; k0 += 16) {
        float4 a0 = *(const float4*)(aptr + k0);
        float4 a1 = *(const float4*)(aptr + k0 + 4);
        float4 b0 = *(const float4*)(Bw + (size_t)(k0 + br) * Nc + n0 + bc);
        float4 b1 = *(const float4*)(Bw + (size_t)(k0 + br) * Nc + n0 + bc + 4);
        if (reluA) {
            a0.x = fmaxf(a0.x, 0.f); a0.y = fmaxf(a0.y, 0.f); a0.z = fmaxf(a0.z, 0.f); a0.w = fmaxf(a0.w, 0.f);
            a1.x = fmaxf(a1.x, 0.f); a1.y = fmaxf(a1.y, 0.f); a1.z = fmaxf(a1.z, 0.f); a1.w = fmaxf(a1.w, 0.f);
        }
        __syncthreads();
        As[lc + 0][lr] = a0.x; As[lc + 1][lr] = a0.y; As[lc + 2][lr] = a0.z; As[lc + 3][lr] = a0.w;
        As[lc + 4][lr] = a1.x; As[lc + 5][lr] = a1.y; As[lc + 6][lr] = a1.z; As[lc + 7][lr] = a1.w;
        *(float4*)&Bs[br][bc] = b0;
        *(float4*)&Bs[br][bc + 4] = b1;
        __syncthreads();
#pragma unroll
        for (int kk = 0; kk < 16; ++kk) {
            float4 av0 = *(const float4*)&As[kk][ty * 8];
            float4 av1 = *(const float4*)&As[kk][ty * 8 + 4];
            float4 bv0 = *(const float4*)&Bs[kk][tx * 8];
            float4 bv1 = *(const float4*)&Bs[kk][tx * 8 + 4];
            float a[8] = {av0.x, av0.y, av0.z, av0.w, av1.x, av1.y, av1.z, av1.w};
            float b[8] = {bv0.x, bv0.y, bv0.z, bv0.w, bv1.x, bv1.y, bv1.z, bv1.w};
#pragma unroll
            for (int i = 0; i < 8; ++i)
#pragma unroll
                for (int j = 0; j < 8; ++j)
                    acc[i][j] = fmaf(a[i], b[j], acc[i][j]);
        }
    }

    const int c = n0 + tx * 8;
    float4 bvl = make_float4(0.f, 0.f, 0.f, 0.f), bvh = bvl;
    if (bias) { bvl = *(const float4*)(bias + c); bvh = *(const float4*)(bias + c + 4); }
#pragma unroll
    for (int i = 0; i < 8; ++i) {
        int r = m0 + ty * 8 + i;
        float4 vl = make_float4(acc[i][0], acc[i][1], acc[i][2], acc[i][3]);
        float4 vh = make_float4(acc[i][4], acc[i][5], acc[i][6], acc[i][7]);
        if (addR) {
            int ar = addIdx ? addIdx[r] : r;
            float4 al = *(const float4*)(addR + (size_t)ar * Nc + c);
            float4 ah = *(const float4*)(addR + (size_t)ar * Nc + c + 4);
            vl.x += al.x; vl.y += al.y; vl.z += al.z; vl.w += al.w;
            vh.x += ah.x; vh.y += ah.y; vh.z += ah.z; vh.w += ah.w;
        }
        vl.x += bvl.x; vl.y += bvl.y; vl.z += bvl.z; vl.w += bvl.w;
        vh.x += bvh.x; vh.y += bvh.y; vh.z += bvh.z; vh.w += bvh.w;
        if (doRelu) {
            vl.x = fmaxf(vl.x, 0.f); vl.y = fmaxf(vl.y, 0.f); vl.z = fmaxf(vl.z, 0.f); vl.w = fmaxf(vl.w, 0.f);
            vh.x = fmaxf(vh.x, 0.f); vh.y = fmaxf(vh.y, 0.f); vh.z = fmaxf(vh.z, 0.f); vh.w = fmaxf(vh.w, 0.f);
        }
        *(float4*)(C + (size_t)r * Nc + c) = vl;
        *(float4*)(C + (size_t)r * Nc + c + 4) = vh;
    }
}

// ---------------- fused recurrent step ----------------
// Block owns rows [m0, m0+128):
//   1) agg[r][:] = sum_p relu(nodeT_in[srcS[p]] + W2eS[p])  -> LDS As[k][m] (transposed)
//   2) node_h = relu(U1x + agg @ U2)                        (regs; optional global write)
//   3) nodeT_out = nodePre + node_h @ W3                    (via As re-transpose)
__global__ __launch_bounds__(256, 2) void fused_step_kernel(
    const float* __restrict__ nodeT_in, const float* __restrict__ W2eS,
    const int* __restrict__ rp, const int* __restrict__ srcS,
    const float* __restrict__ U1x, const float* __restrict__ U2,
    const float* __restrict__ nodePre, const float* __restrict__ W3,
    float* __restrict__ nodeT_out, float* __restrict__ node_h_out,
    int writeNodeH, int doGemm2)
{
    __shared__ float As[128][132];   // 67.6 KB: full-K A panel (transposed)
    __shared__ float Bs[16][132];    // 8.4 KB: B staging
    const int tid = threadIdx.x;
    const int m0 = blockIdx.x << 7;

    // ---- phase 1: aggregation into As (transposed: As[col][row]) ----
    {
        const int cx = (tid & 31) << 2;   // 32 lanes cover 128 cols as float4
        const int ry = tid >> 5;          // 8 rows at a time
        for (int rg = 0; rg < 16; ++rg) {
            const int row = rg * 8 + ry;
            const int n = m0 + row;
            const int p0 = rp[n], p1 = rp[n + 1];
            float4 s = make_float4(0.f, 0.f, 0.f, 0.f);
            for (int p = p0; p < p1; ++p) {
                const int sn = srcS[p];
                float4 t = *(const float4*)(nodeT_in + (size_t)sn * EH + cx);
                float4 w = *(const float4*)(W2eS + (size_t)p * EH + cx);
                s.x += fmaxf(t.x + w.x, 0.f);
                s.y += fmaxf(t.y + w.y, 0.f);
                s.z += fmaxf(t.z + w.z, 0.f);
                s.w += fmaxf(t.w + w.w, 0.f);
            }
            As[cx + 0][row] = s.x;
            As[cx + 1][row] = s.y;
            As[cx + 2][row] = s.z;
            As[cx + 3][row] = s.w;
        }
    }
    __syncthreads();

    const int tx = tid & 15, ty = tid >> 4;
    const int br = tid >> 4, bc = (tid & 15) << 3;

    float acc[8][8];
#pragma unroll
    for (int i = 0; i < 8; ++i)
#pragma unroll
        for (int j = 0; j < 8; ++j) acc[i][j] = 0.0f;

#define FUSED_GEMM(WPTR)                                                          \
    for (int k0 = 0; k0 < 128; k0 += 16) {                                        \
        float4 b0 = *(const float4*)(WPTR + (size_t)(k0 + br) * 128 + bc);        \
        float4 b1 = *(const float4*)(WPTR + (size_t)(k0 + br) * 128 + bc + 4);    \
        __syncthreads();                                                          \
        *(float4*)&Bs[br][bc] = b0;                                               \
        *(float4*)&Bs[br][bc + 4] = b1;                                           \
        __syncthreads();                                                          \
        _Pragma("unroll")                                                         \
        for (int kk = 0; kk < 16; ++kk) {                                         \
            float4 av0 = *(const float4*)&As[k0 + kk][ty * 8];                    \
            float4 av1 = *(const float4*)&As[k0 + kk][ty * 8 + 4];                \
            float4 bv0 = *(const float4*)&Bs[kk][tx * 8];                         \
            float4 bv1 = *(const float4*)&Bs[kk][tx * 8 + 4];                     \
            float a[8] = {av0.x, av0.y, av0.z, av0.w, av1.x, av1.y, av1.z, av1.w};\
            float b[8] = {bv0.x, bv0.y, bv0.z, bv0.w, bv1.x, bv1.y, bv1.z, bv1.w};\
            _Pragma("unroll")                                                     \
            for (int i = 0; i < 8; ++i)                                           \
                _Pragma("unroll")                                                 \
                for (int j = 0; j < 8; ++j)                                       \
                    acc[i][j] = fmaf(a[i], b[j], acc[i][j]);                      \
        }                                                                         \
    }

    // ---- phase 2: node_h = relu(U1x + agg @ U2) ----
    FUSED_GEMM(U2)

    const int c = tx * 8;
#pragma unroll
    for (int i = 0; i < 8; ++i) {
        const int r = m0 + ty * 8 + i;
        float4 u0 = *(const float4*)(U1x + (size_t)r * NH + c);
        float4 u1 = *(const float4*)(U1x + (size_t)r * NH + c + 4);
        acc[i][0] = fmaxf(acc[i][0] + u0.x, 0.f);
        acc[i][1] = fmaxf(acc[i][1] + u0.y, 0.f);
        acc[i][2] = fmaxf(acc[i][2] + u0.z, 0.f);
        acc[i][3] = fmaxf(acc[i][3] + u0.w, 0.f);
        acc[i][4] = fmaxf(acc[i][4] + u1.x, 0.f);
        acc[i][5] = fmaxf(acc[i][5] + u1.y, 0.f);
        acc[i][6] = fmaxf(acc[i][6] + u1.z, 0.f);
        acc[i][7] = fmaxf(acc[i][7] + u1.w, 0.f);
    }
    if (writeNodeH) {
#pragma unroll
        for (int i = 0; i < 8; ++i) {
            const int r = m0 + ty * 8 + i;
            *(float4*)(node_h_out + (size_t)r * NH + c) =
                make_float4(acc[i][0], acc[i][1], acc[i][2], acc[i][3]);
            *(float4*)(node_h_out + (size_t)r * NH + c + 4) =
                make_float4(acc[i][4], acc[i][5], acc[i][6], acc[i][7]);
        }
    }
    if (!doGemm2) return;

    __syncthreads();   // all As reads (GEMM1) done before overwrite
    // re-transpose node_h into As: As[k=col][m=row]
#pragma unroll
    for (int i = 0; i < 8; ++i)
#pragma unroll
        for (int j = 0; j < 8; ++j)
            As[tx * 8 + j][ty * 8 + i] = acc[i][j];
    __syncthreads();

#pragma unroll
    for (int i = 0; i < 8; ++i)
#pragma unroll
        for (int j = 0; j < 8; ++j) acc[i][j] = 0.0f;

    // ---- phase 3: nodeT = nodePre + node_h @ W3 ----
    FUSED_GEMM(W3)
#undef FUSED_GEMM

#pragma unroll
    for (int i = 0; i < 8; ++i) {
        const int r = m0 + ty * 8 + i;
        float4 p0 = *(const float4*)(nodePre + (size_t)r * EH + c);
        float4 p1 = *(const float4*)(nodePre + (size_t)r * EH + c + 4);
        *(float4*)(nodeT_out + (size_t)r * EH + c) =
            make_float4(acc[i][0] + p0.x, acc[i][1] + p0.y, acc[i][2] + p0.z, acc[i][3] + p0.w);
        *(float4*)(nodeT_out + (size_t)r * EH + c + 4) =
            make_float4(acc[i][4] + p1.x, acc[i][5] + p1.y, acc[i][6] + p1.z, acc[i][7] + p1.w);
    }
}

// ---------------- CSR build ----------------
__global__ __launch_bounds__(256) void hist_kernel(const int* __restrict__ dst, int* __restrict__ deg, int E) {
    int e = blockIdx.x * 256 + threadIdx.x;
    if (e < E) atomicAdd(&deg[dst[e]], 1);
}

__global__ __launch_bounds__(256) void scan_block_kernel(const int* __restrict__ deg, int* __restrict__ rp,
                                                         int* __restrict__ bsum) {
    __shared__ int buf[256];
    int tid = threadIdx.x;
    int i = blockIdx.x * 256 + tid;
    int v = deg[i];
    buf[tid] = v;
    __syncthreads();
    for (int off = 1; off < 256; off <<= 1) {
        int t = (tid >= off) ? buf[tid - off] : 0;
        __syncthreads();
        buf[tid] += t;
        __syncthreads();
    }
    rp[i] = buf[tid] - v;
    if (tid == 255) bsum[blockIdx.x] = buf[255];
}

__global__ __launch_bounds__(256) void scan_top_kernel(const int* __restrict__ bsum, int* __restrict__ boff,
                                                       int* __restrict__ rp, int N) {
    __shared__ int buf[256];
    int tid = threadIdx.x;
    int v = bsum[tid];
    buf[tid] = v;
    __syncthreads();
    for (int off = 1; off < 256; off <<= 1) {
        int t = (tid >= off) ? buf[tid - off] : 0;
        __syncthreads();
        buf[tid] += t;
        __syncthreads();
    }
    boff[tid] = buf[tid] - v;
    if (tid == 255) rp[N] = buf[255];
}

__global__ __launch_bounds__(256) void scan_add_kernel(int* __restrict__ rp, int* __restrict__ cursor,
                                                       const int* __restrict__ boff) {
    int tid = threadIdx.x;
    int i = blockIdx.x * 256 + tid;
    int v = rp[i] + boff[blockIdx.x];
    rp[i] = v;
    cursor[i] = v;
}

__global__ __launch_bounds__(256) void scatter_kernel(const int* __restrict__ dst, const int* __restrict__ src,
                                                      int* __restrict__ cursor,
                                                      int* __restrict__ eid, int* __restrict__ srcS, int E) {
    int e = blockIdx.x * 256 + threadIdx.x;
    if (e < E) {
        int p = atomicAdd(&cursor[dst[e]], 1);
        eid[p] = e;
        srcS[p] = src[e];
    }
}

// ---------------- fused x3 GEMM + final dot + threshold ----------------
__global__ __launch_bounds__(256) void x3final_kernel(const float* __restrict__ x2, const float* __restrict__ M3w,
                                                      const float* __restrict__ b3, const float* __restrict__ M4w,
                                                      const float* __restrict__ b4, int* __restrict__ out) {
    __shared__ float As[16][132];
    __shared__ float Bs[16][68];
    __shared__ float red[128][17];
    const int tid = threadIdx.x;
    const int tx = tid & 15;
    const int ty = tid >> 4;
    const int m0 = blockIdx.x << 7;
    const int lr = tid >> 1, lc = (tid & 1) << 3;
    const int br = tid >> 4, bc = (tid & 15) << 2;

    float acc[8][4];
#pragma unroll
    for (int i = 0; i < 8; ++i)
#pragma unroll
        for (int j = 0; j < 4; ++j) acc[i][j] = 0.0f;

    const float* aptr = x2 + (size_t)(m0 + lr) * 128 + lc;
    for (int k0 = 0; k0 < 128; k0 += 16) {
        float4 a0 = *(const float4*)(aptr + k0);
        float4 a1 = *(const float4*)(aptr + k0 + 4);
        float4 bv = *(const float4*)(M3w + (size_t)(k0 + br) * 64 + bc);
        __syncthreads();
        As[lc + 0][lr] = a0.x; As[lc + 1][lr] = a0.y; As[lc + 2][lr] = a0.z; As[lc + 3][lr] = a0.w;
        As[lc + 4][lr] = a1.x; As[lc + 5][lr] = a1.y; As[lc + 6][lr] = a1.z; As[lc + 7][lr] = a1.w;
        *(float4*)&Bs[br][bc] = bv;
        __syncthreads();
#pragma unroll
        for (int kk = 0; kk < 16; ++kk) {
            float4 av0 = *(const float4*)&As[kk][ty * 8];
            float4 av1 = *(const float4*)&As[kk][ty * 8 + 4];
            float4 bv0 = *(const float4*)&Bs[kk][tx * 4];
            float a[8] = {av0.x, av0.y, av0.z, av0.w, av1.x, av1.y, av1.z, av1.w};
            float b[4] = {bv0.x, bv0.y, bv0.z, bv0.w};
#pragma unroll
            for (int i = 0; i < 8; ++i)
#pragma unroll
                for (int j = 0; j < 4; ++j)
                    acc[i][j] = fmaf(a[i], b[j], acc[i][j]);
        }
    }

    const int c = tx * 4;
    float4 b3v = *(const float4*)(b3 + c);
    float4 w4v = *(const float4*)(M4w + c);
#pragma unroll
    for (int i = 0; i < 8; ++i) {
        float p = fmaxf(acc[i][0] + b3v.x, 0.f) * w4v.x
                + fmaxf(acc[i][1] + b3v.y, 0.f) * w4v.y
                + fmaxf(acc[i][2] + b3v.z, 0.f) * w4v.z
                + fmaxf(acc[i][3] + b3v.w, 0.f) * w4v.w;
        red[ty * 8 + i][tx] = p;
    }
    __syncthreads();
    if (tid < 128) {
        float z = b4[0];
#pragma unroll
        for (int j = 0; j < 16; ++j) z += red[tid][j];
        out[m0 + tid] = z >= 0.f ? 1 : 0;
    }
}

extern "C" void kernel_launch(void* const* d_in, const int* in_sizes, int n_in,
                              void* d_out, int out_size, void* d_ws, size_t ws_size,
                              hipStream_t stream)
{
    const float* mol_a = (const float*)d_in[0];
    const float* nf    = (const float*)d_in[1];
    const float* ef    = (const float*)d_in[2];
    const int*   edges = (const int*)d_in[5];
    const int*   batch = (const int*)d_in[6];
    const float* W1  = (const float*)d_in[7];
    const float* W2  = (const float*)d_in[8];
    const float* W3  = (const float*)d_in[9];
    const float* U1  = (const float*)d_in[10];
    const float* U2  = (const float*)d_in[11];
    const float* M1w = (const float*)d_in[12];
    const float* M1b = (const float*)d_in[13];
    const float* M2w = (const float*)d_in[14];
    const float* M2b = (const float*)d_in[15];
    const float* M3w = (const float*)d_in[16];
    const float* M3b = (const float*)d_in[17];
    const float* M4w = (const float*)d_in[18];
    const float* M4b = (const float*)d_in[19];

    const int N = in_sizes[3] / NH;   // 65536
    const int E = in_sizes[4] / EH;   // 262144
    const int B = in_sizes[0] / MA;   // 2048
    const int* srcp = edges;
    const int* dstp = edges + E;

    char* ws = (char*)d_ws;
    size_t off = 0;
    auto alloc = [&](size_t bytes) -> char* {
        char* p = ws + off;
        off = (off + bytes + 255) & ~(size_t)255;
        return p;
    };
    int* deg     = (int*)alloc((size_t)N * 4);
    int* rp      = (int*)alloc(((size_t)N + 1) * 4);
    int* cursor  = (int*)alloc((size_t)N * 4);
    int* bsum    = (int*)alloc(256 * 4);
    int* boff    = (int*)alloc(256 * 4);
    int* eid     = (int*)alloc((size_t)E * 4);
    int* srcS    = (int*)alloc((size_t)E * 4);
    float* nodePre = (float*)alloc((size_t)N * EH * 4);
    float* U1x     = (float*)alloc((size_t)N * NH * 4);
    float* node_h  = (float*)alloc((size_t)N * NH * 4);
    float* nodeTa  = (float*)alloc((size_t)N * EH * 4);
    float* nodeTb  = (float*)alloc((size_t)N * EH * 4);
    float* molPart = (float*)alloc((size_t)B * 256 * 4);
    float* W2eS    = (float*)alloc((size_t)E * EH * 4);
    // MLP phase reuses dead buffers:
    float* x1 = (float*)W2eS;  // [N,256]
    float* x2 = nodeTa;        // [N,128]

    // ---- CSR build (dst is loop-invariant) ----
    hipMemsetAsync(deg, 0, (size_t)N * 4, stream);
    hist_kernel<<<ceil_div(E, 256), 256, 0, stream>>>(dstp, deg, E);
    scan_block_kernel<<<N / 256, 256, 0, stream>>>(deg, rp, bsum);
    scan_top_kernel<<<1, 256, 0, stream>>>(bsum, boff, rp, N);
    scan_add_kernel<<<N / 256, 256, 0, stream>>>(rp, cursor, boff);
    scatter_kernel<<<ceil_div(E, 256), 256, 0, stream>>>(dstp, srcp, cursor, eid, srcS, E);

    // ---- loop-invariant precompute ----
    gemm128_kernel<<<dim3(1, N / 128), 256, 0, stream>>>(nf, W1, nodePre, nullptr, nullptr, nullptr, nullptr, N, NF, EH, 0, 0);
    gemm128_kernel<<<dim3(1, E / 128), 256, 0, stream>>>(ef, W2, W2eS, nullptr, nullptr, nullptr, eid, E, EF, EH, 0, 0);
    gemm128_kernel<<<dim3(1, N / 128), 256, 0, stream>>>(nf, U1, U1x, nullptr, nullptr, nullptr, nullptr, N, NF, NH, 0, 0);

    // ---- step 1 fused: nodeT_1 = nodePre + relu(U1x) @ W3 ----
    gemm128_kernel<<<dim3(1, N / 128), 256, 0, stream>>>(U1x, W3, nodeTa, nodePre, nullptr, nullptr, nullptr, N, NH, EH, 0, 1);

    // ---- steps 2..7: fused agg + GEMM1 + GEMM2, ping-pong nodeT ----
    float* curT = nodeTa;
    float* nxtT = nodeTb;
    for (int s = 0; s < 6; ++s) {
        fused_step_kernel<<<N / 128, 256, 0, stream>>>(curT, W2eS, rp, srcS, U1x, U2, nodePre, W3,
                                                       nxtT, nullptr, 0, 1);
        float* t = curT; curT = nxtT; nxtT = t;
    }
    // ---- step 8: agg + GEMM1 only, write node_h ----
    fused_step_kernel<<<N / 128, 256, 0, stream>>>(curT, W2eS, rp, srcS, U1x, U2, nodePre, W3,
                                                   nxtT, node_h, 1, 0);

    // ---- pick-atom MLP ----
    gemm128_kernel<<<dim3(2, B / 128), 256, 0, stream>>>(mol_a, M1w + 128 * 256, molPart, nullptr, nullptr, M1b, nullptr, B, MA, 256, 0, 0);
    gemm128_kernel<<<dim3(2, N / 128), 256, 0, stream>>>(node_h, M1w, x1, molPart, batch, nullptr, nullptr, N, NH, 256, 1, 0);
    gemm128_kernel<<<dim3(1, N / 128), 256, 0, stream>>>(x1, M2w, x2, nullptr, nullptr, M2b, nullptr, N, 256, 128, 1, 0);
    x3final_kernel<<<N / 128, 256, 0, stream>>>(x2, M3w, M3b, M4w, M4b, (int*)d_out);
}

// Round 6
// 1257.878 us; speedup vs baseline: 1.6949x; 1.1510x over previous
//
#include <hip/hip_runtime.h>
#include <cstddef>

#define NF 64
#define EF 16
#define NH 128
#define EH 128
#define MA 256

static inline int ceil_div(int a, int b) { return (a + b - 1) / b; }

// ---------------- fp32 GEMM, 64x128 tile, 4x8 microtile ----------------
// C = act( reluA?(A[r][K]) @ Bw[K,Nc] + addR[addIdx? addIdx[r]:r] + bias )
// 256 threads. M%64==0, Nc%128==0, K%16==0. Grid: (Nc/128, M/64).
__global__ __launch_bounds__(256) void gemm64_kernel(
    const float* __restrict__ A, const float* __restrict__ Bw,
    float* __restrict__ C,
    const float* __restrict__ addR, const int* __restrict__ addIdx,
    const float* __restrict__ bias,
    int M, int K, int Nc, int doRelu, int reluA)
{
    __shared__ float As[16][68];    // [k][m]
    __shared__ float Bs[16][132];   // [k][n]
    const int tid = threadIdx.x;
    const int tx = tid & 15;        // n: 8 cols each
    const int ty = tid >> 4;        // m: 4 rows each
    const int m0 = blockIdx.y << 6;
    const int n0 = blockIdx.x << 7;

    const int lr = tid >> 2;              // A row 0..63
    const int lc = (tid & 3) << 2;        // A col 0,4,8,12
    const int br = tid >> 4;              // B k-row 0..15
    const int bc = (tid & 15) << 3;       // B col 0..120

    float acc[4][8];
#pragma unroll
    for (int i = 0; i < 4; ++i)
#pragma unroll
        for (int j = 0; j < 8; ++j) acc[i][j] = 0.0f;

    const float* aptr = A + (size_t)(m0 + lr) * K + lc;

    for (int k0 = 0; k0 < K; k0 += 16) {
        float4 a4 = *(const float4*)(aptr + k0);
        float4 b0 = *(const float4*)(Bw + (size_t)(k0 + br) * Nc + n0 + bc);
        float4 b1 = *(const float4*)(Bw + (size_t)(k0 + br) * Nc + n0 + bc + 4);
        if (reluA) {
            a4.x = fmaxf(a4.x, 0.f); a4.y = fmaxf(a4.y, 0.f);
            a4.z = fmaxf(a4.z, 0.f); a4.w = fmaxf(a4.w, 0.f);
        }
        __syncthreads();
        As[lc + 0][lr] = a4.x; As[lc + 1][lr] = a4.y;
        As[lc + 2][lr] = a4.z; As[lc + 3][lr] = a4.w;
        *(float4*)&Bs[br][bc] = b0;
        *(float4*)&Bs[br][bc + 4] = b1;
        __syncthreads();
#pragma unroll
        for (int kk = 0; kk < 16; ++kk) {
            float4 av = *(const float4*)&As[kk][ty * 4];
            float4 bv0 = *(const float4*)&Bs[kk][tx * 8];
            float4 bv1 = *(const float4*)&Bs[kk][tx * 8 + 4];
            float a[4] = {av.x, av.y, av.z, av.w};
            float b[8] = {bv0.x, bv0.y, bv0.z, bv0.w, bv1.x, bv1.y, bv1.z, bv1.w};
#pragma unroll
            for (int i = 0; i < 4; ++i)
#pragma unroll
                for (int j = 0; j < 8; ++j)
                    acc[i][j] = fmaf(a[i], b[j], acc[i][j]);
        }
    }

    const int c = n0 + tx * 8;
    float4 bvl = make_float4(0.f, 0.f, 0.f, 0.f), bvh = bvl;
    if (bias) { bvl = *(const float4*)(bias + c); bvh = *(const float4*)(bias + c + 4); }
#pragma unroll
    for (int i = 0; i < 4; ++i) {
        int r = m0 + ty * 4 + i;
        float4 vl = make_float4(acc[i][0], acc[i][1], acc[i][2], acc[i][3]);
        float4 vh = make_float4(acc[i][4], acc[i][5], acc[i][6], acc[i][7]);
        if (addR) {
            int ar = addIdx ? addIdx[r] : r;
            float4 al = *(const float4*)(addR + (size_t)ar * Nc + c);
            float4 ah = *(const float4*)(addR + (size_t)ar * Nc + c + 4);
            vl.x += al.x; vl.y += al.y; vl.z += al.z; vl.w += al.w;
            vh.x += ah.x; vh.y += ah.y; vh.z += ah.z; vh.w += ah.w;
        }
        vl.x += bvl.x; vl.y += bvl.y; vl.z += bvl.z; vl.w += bvl.w;
        vh.x += bvh.x; vh.y += bvh.y; vh.z += bvh.z; vh.w += bvh.w;
        if (doRelu) {
            vl.x = fmaxf(vl.x, 0.f); vl.y = fmaxf(vl.y, 0.f); vl.z = fmaxf(vl.z, 0.f); vl.w = fmaxf(vl.w, 0.f);
            vh.x = fmaxf(vh.x, 0.f); vh.y = fmaxf(vh.y, 0.f); vh.z = fmaxf(vh.z, 0.f); vh.w = fmaxf(vh.w, 0.f);
        }
        *(float4*)(C + (size_t)r * Nc + c) = vl;
        *(float4*)(C + (size_t)r * Nc + c + 4) = vh;
    }
}

// ---------------- CSR build ----------------
__global__ __launch_bounds__(256) void hist_kernel(const int* __restrict__ dst, int* __restrict__ deg, int E) {
    int e = blockIdx.x * 256 + threadIdx.x;
    if (e < E) atomicAdd(&deg[dst[e]], 1);
}

__global__ __launch_bounds__(256) void scan_block_kernel(const int* __restrict__ deg, int* __restrict__ rp,
                                                         int* __restrict__ bsum) {
    __shared__ int buf[256];
    int tid = threadIdx.x;
    int i = blockIdx.x * 256 + tid;
    int v = deg[i];
    buf[tid] = v;
    __syncthreads();
    for (int off = 1; off < 256; off <<= 1) {
        int t = (tid >= off) ? buf[tid - off] : 0;
        __syncthreads();
        buf[tid] += t;
        __syncthreads();
    }
    rp[i] = buf[tid] - v;
    if (tid == 255) bsum[blockIdx.x] = buf[255];
}

__global__ __launch_bounds__(256) void scan_top_kernel(const int* __restrict__ bsum, int* __restrict__ boff,
                                                       int* __restrict__ rp, int N) {
    __shared__ int buf[256];
    int tid = threadIdx.x;
    int v = bsum[tid];
    buf[tid] = v;
    __syncthreads();
    for (int off = 1; off < 256; off <<= 1) {
        int t = (tid >= off) ? buf[tid - off] : 0;
        __syncthreads();
        buf[tid] += t;
        __syncthreads();
    }
    boff[tid] = buf[tid] - v;
    if (tid == 255) rp[N] = buf[255];
}

__global__ __launch_bounds__(256) void scan_add_kernel(int* __restrict__ rp, int* __restrict__ cursor,
                                                       const int* __restrict__ boff) {
    int tid = threadIdx.x;
    int i = blockIdx.x * 256 + tid;
    int v = rp[i] + boff[blockIdx.x];
    rp[i] = v;
    cursor[i] = v;
}

__global__ __launch_bounds__(256) void scatter_kernel(const int* __restrict__ dst, const int* __restrict__ src,
                                                      int* __restrict__ cursor,
                                                      int* __restrict__ eid, int* __restrict__ srcS, int E) {
    int e = blockIdx.x * 256 + threadIdx.x;
    if (e < E) {
        int p = atomicAdd(&cursor[dst[e]], 1);
        eid[p] = e;
        srcS[p] = src[e];
    }
}

// efS[p][:] = ef[eid[p]][:]  (CSR-ordered edge features, 16 floats/edge)
__global__ __launch_bounds__(256) void gather_ef_kernel(const float* __restrict__ ef, const int* __restrict__ eid,
                                                        float* __restrict__ efS, int E) {
    int idx = blockIdx.x * 256 + threadIdx.x;   // one float4 per thread
    int p = idx >> 2, comp = idx & 3;
    if (p < E) {
        int e = eid[p];
        float4 v = *(const float4*)(ef + (size_t)e * EF + comp * 4);
        *(float4*)(efS + (size_t)p * EF + comp * 4) = v;
    }
}

// ---------------- edge aggregation: agg[n][c] = sum_p relu(nodeT[srcS[p]][c] + (efS[p]@W2)[c]) ----------------
// W2 column-slice (16x4 per lane) held in registers. k ascending 0..15 -> bit-identical to precomputed GEMM.
__global__ __launch_bounds__(256) void agg_kernel(const float* __restrict__ nodeT, const float* __restrict__ efS,
                                                  const int* __restrict__ rp, const int* __restrict__ srcS,
                                                  const float* __restrict__ W2, float* __restrict__ agg) {
    const int n = blockIdx.x * 8 + threadIdx.y;
    const int c = threadIdx.x << 2;   // 32 lanes x float4 = 128 cols
    // preload W2[:, c..c+3] into registers (16 float4s)
    float4 w2r[16];
#pragma unroll
    for (int k = 0; k < 16; ++k) w2r[k] = *(const float4*)(W2 + (size_t)k * EH + c);

    const int p0 = rp[n], p1 = rp[n + 1];
    float4 s = make_float4(0.f, 0.f, 0.f, 0.f);
    for (int p = p0; p < p1; ++p) {
        const int sn = srcS[p];
        const float* ep = efS + (size_t)p * EF;
        float4 e0 = *(const float4*)(ep);
        float4 e1 = *(const float4*)(ep + 4);
        float4 e2 = *(const float4*)(ep + 8);
        float4 e3 = *(const float4*)(ep + 12);
        float ef16[16] = {e0.x, e0.y, e0.z, e0.w, e1.x, e1.y, e1.z, e1.w,
                          e2.x, e2.y, e2.z, e2.w, e3.x, e3.y, e3.z, e3.w};
        float4 w = make_float4(0.f, 0.f, 0.f, 0.f);
#pragma unroll
        for (int k = 0; k < 16; ++k) {
            w.x = fmaf(ef16[k], w2r[k].x, w.x);
            w.y = fmaf(ef16[k], w2r[k].y, w.y);
            w.z = fmaf(ef16[k], w2r[k].z, w.z);
            w.w = fmaf(ef16[k], w2r[k].w, w.w);
        }
        float4 t = *(const float4*)(nodeT + (size_t)sn * EH + c);
        s.x += fmaxf(t.x + w.x, 0.f);
        s.y += fmaxf(t.y + w.y, 0.f);
        s.z += fmaxf(t.z + w.z, 0.f);
        s.w += fmaxf(t.w + w.w, 0.f);
    }
    *(float4*)(agg + (size_t)n * EH + c) = s;
}

// ---------------- fused x3 GEMM + final dot + threshold ----------------
__global__ __launch_bounds__(256) void x3final_kernel(const float* __restrict__ x2, const float* __restrict__ M3w,
                                                      const float* __restrict__ b3, const float* __restrict__ M4w,
                                                      const float* __restrict__ b4, int* __restrict__ out) {
    __shared__ float As[16][132];
    __shared__ float Bs[16][68];
    __shared__ float red[128][17];
    const int tid = threadIdx.x;
    const int tx = tid & 15;
    const int ty = tid >> 4;
    const int m0 = blockIdx.x << 7;
    const int lr = tid >> 1, lc = (tid & 1) << 3;
    const int br = tid >> 4, bc = (tid & 15) << 2;

    float acc[8][4];
#pragma unroll
    for (int i = 0; i < 8; ++i)
#pragma unroll
        for (int j = 0; j < 4; ++j) acc[i][j] = 0.0f;

    const float* aptr = x2 + (size_t)(m0 + lr) * 128 + lc;
    for (int k0 = 0; k0 < 128; k0 += 16) {
        float4 a0 = *(const float4*)(aptr + k0);
        float4 a1 = *(const float4*)(aptr + k0 + 4);
        float4 bv = *(const float4*)(M3w + (size_t)(k0 + br) * 64 + bc);
        __syncthreads();
        As[lc + 0][lr] = a0.x; As[lc + 1][lr] = a0.y; As[lc + 2][lr] = a0.z; As[lc + 3][lr] = a0.w;
        As[lc + 4][lr] = a1.x; As[lc + 5][lr] = a1.y; As[lc + 6][lr] = a1.z; As[lc + 7][lr] = a1.w;
        *(float4*)&Bs[br][bc] = bv;
        __syncthreads();
#pragma unroll
        for (int kk = 0; kk < 16; ++kk) {
            float4 av0 = *(const float4*)&As[kk][ty * 8];
            float4 av1 = *(const float4*)&As[kk][ty * 8 + 4];
            float4 bv0 = *(const float4*)&Bs[kk][tx * 4];
            float a[8] = {av0.x, av0.y, av0.z, av0.w, av1.x, av1.y, av1.z, av1.w};
            float b[4] = {bv0.x, bv0.y, bv0.z, bv0.w};
#pragma unroll
            for (int i = 0; i < 8; ++i)
#pragma unroll
                for (int j = 0; j < 4; ++j)
                    acc[i][j] = fmaf(a[i], b[j], acc[i][j]);
        }
    }

    const int c = tx * 4;
    float4 b3v = *(const float4*)(b3 + c);
    float4 w4v = *(const float4*)(M4w + c);
#pragma unroll
    for (int i = 0; i < 8; ++i) {
        float p = fmaxf(acc[i][0] + b3v.x, 0.f) * w4v.x
                + fmaxf(acc[i][1] + b3v.y, 0.f) * w4v.y
                + fmaxf(acc[i][2] + b3v.z, 0.f) * w4v.z
                + fmaxf(acc[i][3] + b3v.w, 0.f) * w4v.w;
        red[ty * 8 + i][tx] = p;
    }
    __syncthreads();
    if (tid < 128) {
        float z = b4[0];
#pragma unroll
        for (int j = 0; j < 16; ++j) z += red[tid][j];
        out[m0 + tid] = z >= 0.f ? 1 : 0;
    }
}

extern "C" void kernel_launch(void* const* d_in, const int* in_sizes, int n_in,
                              void* d_out, int out_size, void* d_ws, size_t ws_size,
                              hipStream_t stream)
{
    const float* mol_a = (const float*)d_in[0];
    const float* nf    = (const float*)d_in[1];
    const float* ef    = (const float*)d_in[2];
    const int*   edges = (const int*)d_in[5];
    const int*   batch = (const int*)d_in[6];
    const float* W1  = (const float*)d_in[7];
    const float* W2  = (const float*)d_in[8];
    const float* W3  = (const float*)d_in[9];
    const float* U1  = (const float*)d_in[10];
    const float* U2  = (const float*)d_in[11];
    const float* M1w = (const float*)d_in[12];
    const float* M1b = (const float*)d_in[13];
    const float* M2w = (const float*)d_in[14];
    const float* M2b = (const float*)d_in[15];
    const float* M3w = (const float*)d_in[16];
    const float* M3b = (const float*)d_in[17];
    const float* M4w = (const float*)d_in[18];
    const float* M4b = (const float*)d_in[19];

    const int N = in_sizes[3] / NH;   // 65536
    const int E = in_sizes[4] / EH;   // 262144
    const int B = in_sizes[0] / MA;   // 2048
    const int* srcp = edges;
    const int* dstp = edges + E;

    char* ws = (char*)d_ws;
    size_t off = 0;
    auto alloc = [&](size_t bytes) -> char* {
        char* p = ws + off;
        off = (off + bytes + 255) & ~(size_t)255;
        return p;
    };
    int* deg     = (int*)alloc((size_t)N * 4);
    int* rp      = (int*)alloc(((size_t)N + 1) * 4);
    int* cursor  = (int*)alloc((size_t)N * 4);
    int* bsum    = (int*)alloc(256 * 4);
    int* boff    = (int*)alloc(256 * 4);
    int* eid     = (int*)alloc((size_t)E * 4);
    int* srcS    = (int*)alloc((size_t)E * 4);
    float* efS     = (float*)alloc((size_t)E * EF * 4);
    float* nodePre = (float*)alloc((size_t)N * EH * 4);
    float* U1x     = (float*)alloc((size_t)N * NH * 4);
    float* node_h  = (float*)alloc((size_t)N * NH * 4);
    float* nodeTa  = (float*)alloc((size_t)N * EH * 4);
    float* nodeTb  = (float*)alloc((size_t)N * EH * 4);
    float* aggp    = (float*)alloc((size_t)N * EH * 4);
    float* molPart = (float*)alloc((size_t)B * 256 * 4);
    float* x1      = (float*)alloc((size_t)N * 256 * 4);
    float* x2 = nodeTa;   // [N,128] reuse (dead by MLP phase)

    // ---- CSR build (dst is loop-invariant) ----
    hipMemsetAsync(deg, 0, (size_t)N * 4, stream);
    hist_kernel<<<ceil_div(E, 256), 256, 0, stream>>>(dstp, deg, E);
    scan_block_kernel<<<N / 256, 256, 0, stream>>>(deg, rp, bsum);
    scan_top_kernel<<<1, 256, 0, stream>>>(bsum, boff, rp, N);
    scan_add_kernel<<<N / 256, 256, 0, stream>>>(rp, cursor, boff);
    scatter_kernel<<<ceil_div(E, 256), 256, 0, stream>>>(dstp, srcp, cursor, eid, srcS, E);
    gather_ef_kernel<<<ceil_div(E * 4, 256), 256, 0, stream>>>(ef, eid, efS, E);

    // ---- loop-invariant precompute ----
    gemm64_kernel<<<dim3(1, N / 64), 256, 0, stream>>>(nf, W1, nodePre, nullptr, nullptr, nullptr, N, NF, EH, 0, 0);
    gemm64_kernel<<<dim3(1, N / 64), 256, 0, stream>>>(nf, U1, U1x, nullptr, nullptr, nullptr, N, NF, NH, 0, 0);

    // ---- step 1 fused: nodeT_1 = nodePre + relu(U1x) @ W3 ----
    gemm64_kernel<<<dim3(1, N / 64), 256, 0, stream>>>(U1x, W3, nodeTa, nodePre, nullptr, nullptr, N, NH, EH, 0, 1);

    // ---- steps 2..7 ----
    float* curT = nodeTa;
    float* nxtT = nodeTb;
    for (int s = 0; s < 6; ++s) {
        agg_kernel<<<N / 8, dim3(32, 8), 0, stream>>>(curT, efS, rp, srcS, W2, aggp);
        gemm64_kernel<<<dim3(1, N / 64), 256, 0, stream>>>(aggp, U2, node_h, U1x, nullptr, nullptr, N, EH, NH, 1, 0);
        gemm64_kernel<<<dim3(1, N / 64), 256, 0, stream>>>(node_h, W3, nxtT, nodePre, nullptr, nullptr, N, NH, EH, 0, 0);
        float* t = curT; curT = nxtT; nxtT = t;
    }
    // ---- step 8: agg + node update only ----
    agg_kernel<<<N / 8, dim3(32, 8), 0, stream>>>(curT, efS, rp, srcS, W2, aggp);
    gemm64_kernel<<<dim3(1, N / 64), 256, 0, stream>>>(aggp, U2, node_h, U1x, nullptr, nullptr, N, EH, NH, 1, 0);

    // ---- pick-atom MLP ----
    gemm64_kernel<<<dim3(2, B / 64), 256, 0, stream>>>(mol_a, M1w + 128 * 256, molPart, nullptr, nullptr, M1b, B, MA, 256, 0, 0);
    gemm64_kernel<<<dim3(2, N / 64), 256, 0, stream>>>(node_h, M1w, x1, molPart, batch, nullptr, N, NH, 256, 1, 0);
    gemm64_kernel<<<dim3(1, N / 64), 256, 0, stream>>>(x1, M2w, x2, nullptr, nullptr, M2b, N, 256, 128, 1, 0);
    x3final_kernel<<<N / 128, 256, 0, stream>>>(x2, M3w, M3b, M4w, M4b, (int*)d_out);
}